// Round 1
// baseline (1114.026 us; speedup 1.0000x reference)
//
#include <hip/hip_runtime.h>
#include <hip/hip_bf16.h>

#define N_NODES 203769
#define N_EDGES 234355
#define F_IN    165
#define F_HID   128
#define F_OUT   64
#define BN_EPS  1e-5f
#define NB_SCAN 796   // ceil(N_NODES/256)
#define KP      192   // K padded to 6*32 for mfma_16x16x32
#define XST     104   // LDS row stride in shorts (208B = 52 dwords -> 2-way banks, free)

typedef short bf16x8 __attribute__((ext_vector_type(8)));
typedef unsigned short u16x8 __attribute__((ext_vector_type(8)));
typedef float f32x4 __attribute__((ext_vector_type(4)));

__device__ __forceinline__ unsigned short f2bf(float f) {
    unsigned int u = __builtin_bit_cast(unsigned int, f);
    u += 0x7fffu + ((u >> 16) & 1u);   // RNE
    return (unsigned short)(u >> 16);
}

// ---------------------------------------------------------------------------
// CSR build
// ---------------------------------------------------------------------------
__global__ void k_count(const int* __restrict__ dst, int* __restrict__ cnt) {
    int e = blockIdx.x * 256 + threadIdx.x;
    if (e < N_EDGES) atomicAdd(&cnt[dst[e]], 1);
}

__global__ __launch_bounds__(256) void k_scanA(const int* __restrict__ cnt,
                                               int* __restrict__ partials) {
    __shared__ int sm[256];
    int t = threadIdx.x;
    int i = blockIdx.x * 256 + t;
    int v = (i < N_NODES) ? cnt[i] : 0;
    sm[t] = v;
    __syncthreads();
    for (int off = 128; off > 0; off >>= 1) {
        if (t < off) sm[t] += sm[t + off];
        __syncthreads();
    }
    if (t == 0) partials[blockIdx.x] = sm[0];
}

__global__ __launch_bounds__(1024) void k_scanB(int* __restrict__ partials,
                                                int* __restrict__ row_ptr) {
    __shared__ int sm[1024];
    int t = threadIdx.x;
    int v = (t < NB_SCAN) ? partials[t] : 0;
    sm[t] = v;
    __syncthreads();
    for (int off = 1; off < 1024; off <<= 1) {
        int add = (t >= off) ? sm[t - off] : 0;
        __syncthreads();
        sm[t] += add;
        __syncthreads();
    }
    if (t < NB_SCAN) partials[t] = sm[t] - v;   // exclusive
    if (t == NB_SCAN - 1) row_ptr[N_NODES] = sm[t];  // = E
}

__global__ __launch_bounds__(256) void k_scanC(const int* __restrict__ cnt,
                                               const int* __restrict__ partials,
                                               int* __restrict__ row_ptr,
                                               int* __restrict__ cursor,
                                               float* __restrict__ dinv) {
    __shared__ int sm[256];
    int t = threadIdx.x;
    int i = blockIdx.x * 256 + t;
    int v = (i < N_NODES) ? cnt[i] : 0;
    sm[t] = v;
    __syncthreads();
    for (int off = 1; off < 256; off <<= 1) {
        int add = (t >= off) ? sm[t - off] : 0;
        __syncthreads();
        sm[t] += add;
        __syncthreads();
    }
    if (i < N_NODES) {
        int p = partials[blockIdx.x] + sm[t] - v;  // exclusive prefix
        row_ptr[i] = p;
        cursor[i] = p;
        dinv[i] = rsqrtf(1.0f + (float)v);  // +1 self loop
    }
}

__global__ void k_scatter(const int* __restrict__ src, const int* __restrict__ dst,
                          int* __restrict__ cursor, int* __restrict__ csr_src) {
    int e = blockIdx.x * 256 + threadIdx.x;
    if (e < N_EDGES) {
        int pos = atomicAdd(&cursor[dst[e]], 1);
        csr_src[pos] = src[e];
    }
}

// ---------------------------------------------------------------------------
// W1 -> bf16 transposed: w1t[n][k], n=0..127, k=0..191 (zero-pad k>=165)
// ---------------------------------------------------------------------------
__global__ void k_cvt_w(const float* __restrict__ W1, unsigned short* __restrict__ w1t) {
    int i = blockIdx.x * 256 + threadIdx.x;
    if (i < F_HID * KP) {
        int n = i / KP, k = i - n * KP;
        float v = (k < F_IN) ? W1[k * F_HID + n] : 0.0f;
        w1t[i] = f2bf(v);
    }
}

// ---------------------------------------------------------------------------
// GEMM1 via bf16 MFMA: h1s[N,128] = (x[N,165] @ W1[165,128]) * dinv[row]
// Block = 128 rows x 128 cols, 256 thr (4 waves, each 64x64 = 4x4 mfma tiles).
// ---------------------------------------------------------------------------
__global__ __launch_bounds__(256) void k_mfma1(const float* __restrict__ x,
                                               const unsigned short* __restrict__ w1t,
                                               const float* __restrict__ dinv,
                                               float* __restrict__ h1s) {
    __shared__ unsigned short xs[128 * XST];   // 26 KB
    __shared__ unsigned short wsh[128 * XST];  // 26 KB
    const int row0 = blockIdx.x * 128;
    const int t = threadIdx.x;
    const int lane = t & 63;
    const int wv = t >> 6;
    const int l16 = lane & 15;
    const int quad = lane >> 4;
    const int m0w = (wv >> 1) * 64;
    const int n0w = (wv & 1) * 64;

    f32x4 acc[4][4];
#pragma unroll
    for (int mt = 0; mt < 4; mt++)
#pragma unroll
        for (int nt = 0; nt < 4; nt++)
            acc[mt][nt] = (f32x4){0.0f, 0.0f, 0.0f, 0.0f};

    for (int cc = 0; cc < 2; cc++) {
        const int kc = cc * 96;
        // stage x chunk (fp32 -> bf16)
#pragma unroll
        for (int s = 0; s < 6; s++) {
            int g = t + s * 256;          // 0..1535
            int r = g / 12;
            int c8 = (g - r * 12) * 8;    // 0,8,...,88
            int grow = row0 + r;
            u16x8 uv;
            if (grow < N_NODES) {
                const float* xr = x + (size_t)grow * F_IN;
#pragma unroll
                for (int j = 0; j < 8; j++) {
                    int k = kc + c8 + j;
                    uv[j] = (k < F_IN) ? f2bf(xr[k]) : (unsigned short)0;
                }
            } else {
#pragma unroll
                for (int j = 0; j < 8; j++) uv[j] = 0;
            }
            *(u16x8*)&xs[r * XST + c8] = uv;
        }
        // stage w chunk (already bf16)
#pragma unroll
        for (int s = 0; s < 6; s++) {
            int g = t + s * 256;
            int r = g / 12;
            int c8 = (g - r * 12) * 8;
            *(u16x8*)&wsh[r * XST + c8] = *(const u16x8*)&w1t[r * KP + kc + c8];
        }
        __syncthreads();

#pragma unroll
        for (int ks = 0; ks < 96; ks += 32) {
            int kf = ks + quad * 8;
            bf16x8 a[4], b[4];
#pragma unroll
            for (int mt = 0; mt < 4; mt++)
                a[mt] = *(const bf16x8*)&xs[(m0w + mt * 16 + l16) * XST + kf];
#pragma unroll
            for (int nt = 0; nt < 4; nt++)
                b[nt] = *(const bf16x8*)&wsh[(n0w + nt * 16 + l16) * XST + kf];
#pragma unroll
            for (int mt = 0; mt < 4; mt++)
#pragma unroll
                for (int nt = 0; nt < 4; nt++)
                    acc[mt][nt] = __builtin_amdgcn_mfma_f32_16x16x32_bf16(
                        a[mt], b[nt], acc[mt][nt], 0, 0, 0);
        }
        __syncthreads();
    }

    // epilogue: C/D col = lane&15, row = quad*4 + reg; scale by dinv[row]
#pragma unroll
    for (int mt = 0; mt < 4; mt++) {
#pragma unroll
        for (int rg = 0; rg < 4; rg++) {
            int grow = row0 + m0w + mt * 16 + quad * 4 + rg;
            if (grow < N_NODES) {
                float dv = dinv[grow];
                float* orow = h1s + (size_t)grow * F_HID + n0w + l16;
#pragma unroll
                for (int nt = 0; nt < 4; nt++)
                    orow[nt * 16] = acc[mt][nt][rg] * dv;
            }
        }
    }
}

// ---------------------------------------------------------------------------
// CSR aggregation + fused BN stats:
// out[d,:] = dinv[d] * (hs[d,:] + sum_{s in in(d)} hs[s,:])
//
// R5: latency-bound fix. ILV=4 independent node chains per thread (row_ptr,
// self-row, csr_src, gather loads for 4 nodes all issue before any wait) +
// grid 1024->2048 (fills all 8192 wave slots). Counters said 1.19 TB/s @
// 2.9% VALUBusy, 27% occupancy: pure pointer-chase latency, traffic already
// minimal (gathers L3-absorbed).
// ---------------------------------------------------------------------------
template <int C, int TPN, int NPB, int ILV>
__global__ __launch_bounds__(256) void k_aggr(const float* __restrict__ hs,
                                              const int* __restrict__ row_ptr,
                                              const int* __restrict__ csr_src,
                                              const float* __restrict__ dinv,
                                              float* __restrict__ out,
                                              float* __restrict__ gsum,
                                              float* __restrict__ gsumsq) {
    const int t = threadIdx.x;
    const int q = t & (TPN - 1);
    const int slot = t / TPN;
    const int STRIDE = NPB * ILV;
    float s0 = 0, s1 = 0, s2 = 0, s3 = 0;
    float q0 = 0, q1 = 0, q2 = 0, q3 = 0;

    for (int base = blockIdx.x * STRIDE + slot; base < N_NODES;
         base += gridDim.x * STRIDE) {
        int node[ILV], e0[ILV], e1[ILV];
        float4 acc[ILV];
        float dv[ILV];
        // issue all row_ptr loads (independent)
#pragma unroll
        for (int j = 0; j < ILV; j++) {
            node[j] = base + j * NPB;
            bool ok = node[j] < N_NODES;
            e0[j] = ok ? row_ptr[node[j]] : 0;
            e1[j] = ok ? row_ptr[node[j] + 1] : 0;
        }
        // issue all self-row loads + dinv (independent of row_ptr)
#pragma unroll
        for (int j = 0; j < ILV; j++) {
            if (node[j] < N_NODES) {
                acc[j] = *(const float4*)&hs[(size_t)node[j] * C + q * 4];
                dv[j] = dinv[node[j]];
            } else {
                acc[j] = make_float4(0.f, 0.f, 0.f, 0.f);
                dv[j] = 0.f;
            }
        }
        // interleaved edge loops: 4 independent chase chains in flight
        while (true) {
            bool act[ILV];
            bool any = false;
#pragma unroll
            for (int j = 0; j < ILV; j++) {
                act[j] = (e0[j] < e1[j]);
                any = any || act[j];
            }
            if (!any) break;
            int sidx[ILV];
#pragma unroll
            for (int j = 0; j < ILV; j++)
                sidx[j] = act[j] ? csr_src[e0[j]] : 0;
#pragma unroll
            for (int j = 0; j < ILV; j++) {
                if (act[j]) {
                    const float4 v =
                        *(const float4*)&hs[(size_t)sidx[j] * C + q * 4];
                    acc[j].x += v.x; acc[j].y += v.y;
                    acc[j].z += v.z; acc[j].w += v.w;
                }
                e0[j]++;
            }
        }
        // scale, store, accumulate BN stats
#pragma unroll
        for (int j = 0; j < ILV; j++) {
            if (node[j] < N_NODES) {
                acc[j].x *= dv[j]; acc[j].y *= dv[j];
                acc[j].z *= dv[j]; acc[j].w *= dv[j];
                *(float4*)&out[(size_t)node[j] * C + q * 4] = acc[j];
                s0 += acc[j].x; s1 += acc[j].y; s2 += acc[j].z; s3 += acc[j].w;
                q0 = fmaf(acc[j].x, acc[j].x, q0);
                q1 = fmaf(acc[j].y, acc[j].y, q1);
                q2 = fmaf(acc[j].z, acc[j].z, q2);
                q3 = fmaf(acc[j].w, acc[j].w, q3);
            }
        }
    }

    __shared__ float sm[256 * 4];
    __shared__ float sq[256 * 4];
    sm[t * 4 + 0] = s0; sm[t * 4 + 1] = s1; sm[t * 4 + 2] = s2; sm[t * 4 + 3] = s3;
    sq[t * 4 + 0] = q0; sq[t * 4 + 1] = q1; sq[t * 4 + 2] = q2; sq[t * 4 + 3] = q3;
    __syncthreads();
    if (t < TPN) {
#pragma unroll
        for (int sl = 1; sl < NPB; sl++) {
            int u = (sl * TPN + t) * 4;
            s0 += sm[u + 0]; s1 += sm[u + 1]; s2 += sm[u + 2]; s3 += sm[u + 3];
            q0 += sq[u + 0]; q1 += sq[u + 1]; q2 += sq[u + 2]; q3 += sq[u + 3];
        }
        atomicAdd(&gsum[t * 4 + 0], s0); atomicAdd(&gsum[t * 4 + 1], s1);
        atomicAdd(&gsum[t * 4 + 2], s2); atomicAdd(&gsum[t * 4 + 3], s3);
        atomicAdd(&gsumsq[t * 4 + 0], q0); atomicAdd(&gsumsq[t * 4 + 1], q1);
        atomicAdd(&gsumsq[t * 4 + 2], q2); atomicAdd(&gsumsq[t * 4 + 3], q3);
    }
}

// scale = g*rstd ; shift = be - mean*scale
__global__ void k_bn_finalize(const float* gsum, const float* gsumsq,
                              const float* g, const float* be,
                              float* sc, float* sh, int C) {
    int c = threadIdx.x;
    if (c < C) {
        const float invn = 1.0f / (float)N_NODES;
        float mean = gsum[c] * invn;
        float var = gsumsq[c] * invn - mean * mean;
        float rstd = rsqrtf(var + BN_EPS);
        float scale = g[c] * rstd;
        sc[c] = scale;
        sh[c] = fmaf(-mean, scale, be[c]);
    }
}

// ---------------------------------------------------------------------------
// GEMM2: h2s = (relu(bn1(out1)) @ W2) * dinv[row]
// ---------------------------------------------------------------------------
__global__ __launch_bounds__(256) void k_gemm2(const float* __restrict__ out1,
                                               const float* __restrict__ sc1,
                                               const float* __restrict__ sh1,
                                               const float* __restrict__ W2,
                                               const float* __restrict__ dinv,
                                               float* __restrict__ h2s) {
    __shared__ float xs[64 * 132];  // 33.8 KB
    const int row0 = blockIdx.x * 64;
    const int t = threadIdx.x;
    {
        const float* src = out1 + (size_t)row0 * F_HID;
        const int maxe = (N_NODES - row0) * F_HID;
        for (int fi = t; fi < 64 * F_HID; fi += 256) {
            int r = fi >> 7;
            int c = fi & 127;
            float v = (fi < maxe) ? src[fi] : 0.0f;
            v = fmaf(v, sc1[c], sh1[c]);
            xs[r * 132 + c] = fmaxf(v, 0.0f);
        }
    }
    __syncthreads();

    const int c0 = (t & 15) * 4;
    const int r0 = (t >> 4) * 4;

    float acc[4][4];
#pragma unroll
    for (int r = 0; r < 4; r++)
#pragma unroll
        for (int c = 0; c < 4; c++) acc[r][c] = 0.0f;

#pragma unroll 2
    for (int k4 = 0; k4 < F_HID; k4 += 4) {
        float4 xv[4];
#pragma unroll
        for (int r = 0; r < 4; r++)
            xv[r] = *(const float4*)&xs[(r0 + r) * 132 + k4];
        float4 w[4];
#pragma unroll
        for (int j = 0; j < 4; j++)
            w[j] = *(const float4*)&W2[(k4 + j) * F_OUT + c0];
#pragma unroll
        for (int r = 0; r < 4; r++) {
            const float xr[4] = {xv[r].x, xv[r].y, xv[r].z, xv[r].w};
#pragma unroll
            for (int j = 0; j < 4; j++) {
                acc[r][0] = fmaf(xr[j], w[j].x, acc[r][0]);
                acc[r][1] = fmaf(xr[j], w[j].y, acc[r][1]);
                acc[r][2] = fmaf(xr[j], w[j].z, acc[r][2]);
                acc[r][3] = fmaf(xr[j], w[j].w, acc[r][3]);
            }
        }
    }
#pragma unroll
    for (int r = 0; r < 4; r++) {
        int row = row0 + r0 + r;
        if (row < N_NODES) {
            float dv = dinv[row];
            float4 o = {acc[r][0] * dv, acc[r][1] * dv, acc[r][2] * dv, acc[r][3] * dv};
            *(float4*)&h2s[(size_t)row * F_OUT + c0] = o;
        }
    }
}

// ---------------------------------------------------------------------------
// Final: hf = bn2(out2) -> d_out; z = relu(hf@Wp1+bp1)@Wp2+bp2
// ---------------------------------------------------------------------------
__global__ __launch_bounds__(256) void k_final(const float* __restrict__ out2,
                                               const float* __restrict__ sc2,
                                               const float* __restrict__ sh2,
                                               const float* __restrict__ Wp1,
                                               const float* __restrict__ bp1,
                                               const float* __restrict__ Wp2,
                                               const float* __restrict__ bp2,
                                               float* __restrict__ out) {
    __shared__ float hs[64 * 68];   // 17.4 KB
    __shared__ float as_[64 * 68];  // 17.4 KB
    const int row0 = blockIdx.x * 64;
    const int t = threadIdx.x;

    {
        const float4* src = (const float4*)out2;
        float4* dsth = (float4*)out;
#pragma unroll
        for (int i = 0; i < 4; i++) {
            int f4 = t + i * 256;         // 0..1023
            int r = f4 >> 4;
            int c4 = f4 & 15;
            int grow = row0 + r;
            float4 v = {0, 0, 0, 0};
            if (grow < N_NODES) v = src[(size_t)grow * 16 + c4];
            int c = c4 * 4;
            v.x = fmaf(v.x, sc2[c + 0], sh2[c + 0]);
            v.y = fmaf(v.y, sc2[c + 1], sh2[c + 1]);
            v.z = fmaf(v.z, sc2[c + 2], sh2[c + 2]);
            v.w = fmaf(v.w, sc2[c + 3], sh2[c + 3]);
            if (grow < N_NODES) dsth[(size_t)grow * 16 + c4] = v;
            *(float4*)&hs[r * 68 + c] = v;
        }
    }
    __syncthreads();

    const int c0 = (t & 15) * 4;
    const int r0 = (t >> 4) * 4;

    // GEMM A: a = relu(hs @ Wp1 + bp1)
    {
        float acc[4][4];
#pragma unroll
        for (int r = 0; r < 4; r++)
#pragma unroll
            for (int c = 0; c < 4; c++) acc[r][c] = 0.0f;
#pragma unroll 2
        for (int k4 = 0; k4 < 64; k4 += 4) {
            float4 xv[4];
#pragma unroll
            for (int r = 0; r < 4; r++)
                xv[r] = *(const float4*)&hs[(r0 + r) * 68 + k4];
            float4 w[4];
#pragma unroll
            for (int j = 0; j < 4; j++)
                w[j] = *(const float4*)&Wp1[(k4 + j) * 64 + c0];
#pragma unroll
            for (int r = 0; r < 4; r++) {
                const float xr[4] = {xv[r].x, xv[r].y, xv[r].z, xv[r].w};
#pragma unroll
                for (int j = 0; j < 4; j++) {
                    acc[r][0] = fmaf(xr[j], w[j].x, acc[r][0]);
                    acc[r][1] = fmaf(xr[j], w[j].y, acc[r][1]);
                    acc[r][2] = fmaf(xr[j], w[j].z, acc[r][2]);
                    acc[r][3] = fmaf(xr[j], w[j].w, acc[r][3]);
                }
            }
        }
        float4 b = *(const float4*)&bp1[c0];
#pragma unroll
        for (int r = 0; r < 4; r++) {
            float4 o = {fmaxf(acc[r][0] + b.x, 0.0f), fmaxf(acc[r][1] + b.y, 0.0f),
                        fmaxf(acc[r][2] + b.z, 0.0f), fmaxf(acc[r][3] + b.w, 0.0f)};
            *(float4*)&as_[(r0 + r) * 68 + c0] = o;
        }
    }
    __syncthreads();

    // GEMM B: z = a @ Wp2 + bp2
    {
        float acc[4][4];
#pragma unroll
        for (int r = 0; r < 4; r++)
#pragma unroll
            for (int c = 0; c < 4; c++) acc[r][c] = 0.0f;
#pragma unroll 2
        for (int k4 = 0; k4 < 64; k4 += 4) {
            float4 xv[4];
#pragma unroll
            for (int r = 0; r < 4; r++)
                xv[r] = *(const float4*)&as_[(r0 + r) * 68 + k4];
            float4 w[4];
#pragma unroll
            for (int j = 0; j < 4; j++)
                w[j] = *(const float4*)&Wp2[(k4 + j) * 64 + c0];
#pragma unroll
            for (int r = 0; r < 4; r++) {
                const float xr[4] = {xv[r].x, xv[r].y, xv[r].z, xv[r].w};
#pragma unroll
                for (int j = 0; j < 4; j++) {
                    acc[r][0] = fmaf(xr[j], w[j].x, acc[r][0]);
                    acc[r][1] = fmaf(xr[j], w[j].y, acc[r][1]);
                    acc[r][2] = fmaf(xr[j], w[j].z, acc[r][2]);
                    acc[r][3] = fmaf(xr[j], w[j].w, acc[r][3]);
                }
            }
        }
        float4 b = *(const float4*)&bp2[c0];
        float* zout = out + (size_t)N_NODES * 64;
#pragma unroll
        for (int r = 0; r < 4; r++) {
            int row = row0 + r0 + r;
            if (row < N_NODES) {
                float4 o = {acc[r][0] + b.x, acc[r][1] + b.y,
                            acc[r][2] + b.z, acc[r][3] + b.w};
                *(float4*)&zout[(size_t)row * 64 + c0] = o;
            }
        }
    }
}

// ---------------------------------------------------------------------------
// launch
// ---------------------------------------------------------------------------
extern "C" void kernel_launch(void* const* d_in, const int* in_sizes, int n_in,
                              void* d_out, int out_size, void* d_ws, size_t ws_size,
                              hipStream_t stream) {
    const float* x   = (const float*)d_in[0];
    const int*   ei  = (const int*)d_in[1];
    const float* W1  = (const float*)d_in[2];
    // b1 (d_in[3]) skipped: column-constant shift cancelled by BN1
    const float* g1  = (const float*)d_in[4];
    const float* be1 = (const float*)d_in[5];
    const float* W2  = (const float*)d_in[6];
    // b2 (d_in[7]) skipped: cancelled by BN2
    const float* g2  = (const float*)d_in[8];
    const float* be2 = (const float*)d_in[9];
    const float* Wp1 = (const float*)d_in[10];
    const float* bp1 = (const float*)d_in[11];
    const float* Wp2 = (const float*)d_in[12];
    const float* bp2 = (const float*)d_in[13];

    const int* src = ei;            // edge_index[0]
    const int* dst = ei + N_EDGES;  // edge_index[1]

    float* ws = (float*)d_ws;
    float* A    = ws;                          // h1s (N*128) / h2s (N*64)
    float* B    = A + (size_t)N_NODES * 128;   // out1 (N*128) / out2 (N*64)
    float* dinv = B + (size_t)N_NODES * 128;   // N
    float* st   = dinv + N_NODES;              // 768 floats of stats
    float* s1   = st;        float* s1q  = st + 128;
    float* sc1  = st + 256;  float* sh1  = st + 384;
    float* s2   = st + 512;  float* s2q  = st + 576;
    float* sc2  = st + 640;  float* sh2  = st + 704;
    int* cnt      = (int*)(st + 768);          // N
    int* row_ptr  = cnt + N_NODES;             // N+1
    int* cursor   = row_ptr + N_NODES + 1;     // N
    int* csr_src  = cursor + N_NODES;          // E
    int* partials = csr_src + N_EDGES;         // NB_SCAN
    unsigned short* w1t = (unsigned short*)(partials + NB_SCAN);  // 128*192 bf16

    hipMemsetAsync(st, 0, (768 + N_NODES) * sizeof(float), stream);

    const int EB = (N_EDGES + 255) / 256;
    const int GB64 = (N_NODES + 63) / 64;
    const int GB128 = (N_NODES + 127) / 128;

    // CSR build + dinv (+ W1 conversion, independent)
    k_count<<<EB, 256, 0, stream>>>(dst, cnt);
    k_cvt_w<<<(F_HID * KP + 255) / 256, 256, 0, stream>>>(W1, w1t);
    k_scanA<<<NB_SCAN, 256, 0, stream>>>(cnt, partials);
    k_scanB<<<1, 1024, 0, stream>>>(partials, row_ptr);
    k_scanC<<<NB_SCAN, 256, 0, stream>>>(cnt, partials, row_ptr, cursor, dinv);
    k_scatter<<<EB, 256, 0, stream>>>(src, dst, cursor, csr_src);

    // layer 1 (MFMA bf16 GEMM)
    k_mfma1<<<GB128, 256, 0, stream>>>(x, w1t, dinv, A);
    k_aggr<128, 32, 8, 4><<<2048, 256, 0, stream>>>(A, row_ptr, csr_src, dinv, B, s1, s1q);
    k_bn_finalize<<<1, 128, 0, stream>>>(s1, s1q, g1, be1, sc1, sh1, 128);

    // layer 2 (BN1+relu fused into GEMM2 load)
    k_gemm2<<<GB64, 256, 0, stream>>>(B, sc1, sh1, W2, dinv, A);
    k_aggr<64, 16, 16, 4><<<2048, 256, 0, stream>>>(A, row_ptr, csr_src, dinv, B, s2, s2q);
    k_bn_finalize<<<1, 64, 0, stream>>>(s2, s2q, g2, be2, sc2, sh2, 64);

    // BN2-apply + MLP head, writes both outputs
    k_final<<<GB64, 256, 0, stream>>>(B, sc2, sh2, Wp1, bp1, Wp2, bp2, (float*)d_out);
}